// Round 9
// baseline (159.519 us; speedup 1.0000x reference)
//
#include <hip/hip_runtime.h>
#include <hip/hip_bf16.h>
#include <cstddef>

// Problem constants
#define B_ROWS 16384
#define SDIM 512
#define ADIM 64
#define KDIM 576    // SDIM + ADIM
#define KPAD1 640   // KDIM padded to 10 K-tiles of 64
#define HID 1024
#define NQ 64

// prep segmentation (8-element work items, all boundaries 64-aligned)
#define SEG0_ITEMS (B_ROWS * (SDIM / 8))
#define SEG1_ITEMS (B_ROWS * (ADIM / 8))
#define SEG2_ITEMS (B_ROWS * ((KPAD1 - KDIM) / 8))
#define EW_ITEMS (SEG0_ITEMS + SEG1_ITEMS + SEG2_ITEMS)
#define EW_BLOCKS 2048
#define T1_BLOCKS 640
#define T2_BLOCKS 1024
#define PREP_BLOCKS (EW_BLOCKS + T1_BLOCKS + T2_BLOCKS + 1)

typedef __attribute__((ext_vector_type(8))) __bf16 bf16x8;
typedef __attribute__((ext_vector_type(4))) float f32x4;

static __device__ __forceinline__ float bf2f(unsigned short u) {
  union { unsigned int i; float f; } x; x.i = ((unsigned int)u) << 16; return x.f;
}
static __device__ __forceinline__ unsigned short f2bf(float f) {
  union { float f; unsigned int i; } x; x.f = f;
  unsigned int i = x.i + (0x7fffu + ((x.i >> 16) & 1u)); // RNE
  return (unsigned short)(i >> 16);
}

static __device__ __forceinline__ void gload_lds16(const unsigned short* g, unsigned short* l) {
  __builtin_amdgcn_global_load_lds(
      (const __attribute__((address_space(1))) void*)(const void*)g,
      (__attribute__((address_space(3))) void*)(void*)l, 16, 0, 0);
}

static __device__ __forceinline__ ushort4 cvt8lo(float4 a) {
  ushort4 o; o.x = f2bf(a.x); o.y = f2bf(a.y); o.z = f2bf(a.z); o.w = f2bf(a.w);
  return o;
}

// ---- transpose helper ----
static __device__ __forceinline__ void transpose_body(
    const float* __restrict__ W, unsigned short* __restrict__ Wb,
    int Kin, int Kpad, int N, int k0, int n0, unsigned short* tile) {
  const int tx = threadIdx.x & 31, ty = threadIdx.x >> 5;
#pragma unroll
  for (int i = 0; i < 32; i += 8) {
    const int k = k0 + ty + i;
    tile[(ty + i) * 33 + tx] = (k < Kin) ? f2bf(W[(size_t)k * N + n0 + tx]) : (unsigned short)0;
  }
  __syncthreads();
#pragma unroll
  for (int i = 0; i < 32; i += 8)
    Wb[(size_t)(n0 + ty + i) * Kpad + k0 + tx] = tile[tx * 33 + ty + i];
}

// ---- fused prep: pack_x (3-segment, grid-stride) + transposes + qoff ----
__global__ __launch_bounds__(256) void prep_k(
    const float* __restrict__ state, const float* __restrict__ action,
    const float* __restrict__ W1, const float* __restrict__ W2,
    const float* __restrict__ Wq1, const float* __restrict__ bq1,
    const float* __restrict__ Wq2, const float* __restrict__ bq2,
    const float* __restrict__ Wh, const float* __restrict__ bh,
    unsigned short* __restrict__ xb, unsigned short* __restrict__ w1b,
    unsigned short* __restrict__ w2b, float* __restrict__ qoff) {
  __shared__ unsigned short tile[32 * 33];
  const int b = blockIdx.x;
  if (b < EW_BLOCKS) {
    for (int i = b * 256 + (int)threadIdx.x; i < EW_ITEMS; i += EW_BLOCKS * 256) {
      if (i < SEG0_ITEMS) {
        const int r = i >> 6, c = (i & 63) << 3;
        const float* sp = state + (size_t)r * SDIM + c;
        float4 a = *(const float4*)sp;
        float4 bb = *(const float4*)(sp + 4);
        unsigned short* yp = xb + (size_t)r * KPAD1 + c;
        *(ushort4*)yp = cvt8lo(a);
        *(ushort4*)(yp + 4) = cvt8lo(bb);
      } else if (i < SEG0_ITEMS + SEG1_ITEMS) {
        const int j = i - SEG0_ITEMS;
        const int r = j >> 3, ca = (j & 7) << 3;
        const float* ap = action + (size_t)r * ADIM + ca;
        float4 a = *(const float4*)ap;
        float4 bb = *(const float4*)(ap + 4);
        unsigned short* yp = xb + (size_t)r * KPAD1 + SDIM + ca;
        *(ushort4*)yp = cvt8lo(a);
        *(ushort4*)(yp + 4) = cvt8lo(bb);
      } else {
        const int j = i - SEG0_ITEMS - SEG1_ITEMS;
        const int r = j >> 3, cz = (j & 7) << 3;
        unsigned short* yp = xb + (size_t)r * KPAD1 + KDIM + cz;
        ushort4 z = {0, 0, 0, 0};
        *(ushort4*)yp = z;
        *(ushort4*)(yp + 4) = z;
      }
    }
  } else if (b < EW_BLOCKS + T1_BLOCKS) {
    const int t = b - EW_BLOCKS;
    transpose_body(W1, w1b, KDIM, KPAD1, HID, (t / 32) * 32, (t % 32) * 32, tile);
  } else if (b < EW_BLOCKS + T1_BLOCKS + T2_BLOCKS) {
    const int t = b - EW_BLOCKS - T1_BLOCKS;
    transpose_body(W2, w2b, HID, HID, HID, (t / 32) * 32, (t % 32) * 32, tile);
  } else {
    const int q = threadIdx.x;
    if (q < NQ) {
      const float tau = ((float)q + 0.5f) * (1.0f / (float)NQ);
      float t1[64];
#pragma unroll
      for (int k = 0; k < 64; ++k) t1[k] = fmaxf(fmaf(tau, Wq1[k], bq1[k]), 0.f);
      float acc = bh[0];
#pragma unroll 1
      for (int j = 0; j < 64; ++j) {
        float t2 = bq2[j];
#pragma unroll
        for (int k = 0; k < 64; ++k) t2 = fmaf(t1[k], Wq2[k * 64 + j], t2);
        acc = fmaf(t2, Wh[HID + j], acc);
      }
      qoff[q] = acc;
    }
  }
}

// LN+ReLU transform of 8 bf16 (one uint4), write 16B to LDS.
// gb[0..7] = gamma cols, gb[8..15] = beta cols (already sce-aligned).
static __device__ __forceinline__ void ln_wr8(
    unsigned short* dst, uint4 u, float mu, float rs, const float* gb) {
  uint4 ov;
  unsigned int* op = (unsigned int*)&ov;
  const unsigned int* ip = (const unsigned int*)&u;
#pragma unroll
  for (int i = 0; i < 4; ++i) {
    float x0 = bf2f((unsigned short)(ip[i] & 0xffffu));
    float x1 = bf2f((unsigned short)(ip[i] >> 16));
    float y0 = fmaxf((x0 - mu) * rs * gb[2 * i] + gb[8 + 2 * i], 0.f);
    float y1 = fmaxf((x1 - mu) * rs * gb[2 * i + 1] + gb[8 + 2 * i + 1], 0.f);
    op[i] = (unsigned int)f2bf(y0) | ((unsigned int)f2bf(y1) << 16);
  }
  *(uint4*)dst = ov;
}

// ============================================================================
// 256x256 8-phase bf16 GEMM (r5-measured skeleton), two modes:
//  FUSED=false: A via global_load_lds; row-stats atomicAdd epilogue
//               (f32 sum/sumsq of acc+bias per output row).
//  FUSED=true : A reg-staged; LN1+ReLU applied during the LDS write
//               (reads raw pre-LN A + row stats + g/be cols). B unchanged.
// FUSED A ledger: ALD/GBLD at P3/P4 feed AWR at P5/P6 (tile t+2, buf0);
// ALD/GBLD at P7/P8 feed next-P1/P2 (tile t+3 = next iter's t+1, buf1).
// 24 vmem/iter; explicit waits vmcnt(12) at end-P4 (drains prev-P7/P8 B(t+1)
// before P5 reads) and end-P8 (drains P3/P4 B(t+2) before next-P1 reads);
// compiler auto-waits at AWR reg-uses drain everything older (oldest-first).
// AWR dest = wave base + l*16  (gload_lds adds lane*16 in HW; explicit
// ds_write must add it manually — r8's bug was omitting it).
// ============================================================================
template <bool FUSED>
__global__ __launch_bounds__(512, 2) void gemm8_k(
    const unsigned short* __restrict__ A, const unsigned short* __restrict__ Bt,
    const float* __restrict__ bias, unsigned short* __restrict__ C,
    float* __restrict__ stats, const float* __restrict__ gLn,
    const float* __restrict__ beLn, int N, int K, int NT) {
  extern __shared__ unsigned short sm[];
  const int tid = threadIdx.x;
  const int w = tid >> 6, l = tid & 63;

  // bijective XCD chunk swizzle (gridDim.x % 8 == 0)
  const int cpx = (int)gridDim.x >> 3;
  int bid = (int)blockIdx.x;
  bid = (bid & 7) * cpx + (bid >> 3);
  const int nb = N >> 8;
  const int m0 = (bid / nb) << 8, n0 = (bid % nb) << 8;

  const int srow0 = w * 8 + (l >> 3);
  const int sce = ((((l & 7) << 4) ^ ((srow0 & 4) << 3)) >> 1);

  const int aB = (w >> 2) * 16384;
  const int bB = 65536 + ((w & 3) >> 1) * 16384;
  const int lr = (l & 15) << 7;
  const int bRow = (w & 1) << 13;
  const int cSw = (((l >> 4) << 4) ^ ((l & 4) << 3));

  f32x4 acc[8][4] = {};
  bf16x8 ra[2][4], rb[2][4];

  // FUSED state
  float mu4[4], rs4[4];
  uint4 rA[2], rB[2];       // A halves in flight (h0 rows / h1 rows)
  float gbA[16], gbB[16];   // [0..7]=gamma, [8..15]=beta for a K-tile

#define AF(d, mi, kk) (*(const bf16x8*)(sm + ((aB + (d)*32768 + (mi)*2048 + lr + cSw + ((kk) << 6)) >> 1)))
#define BFR(d, ni, kk) (*(const bf16x8*)(sm + ((bB + (d)*32768 + bRow + (ni)*2048 + lr + cSw + ((kk) << 6)) >> 1)))
#define STGA(d, h, kt) do { \
    const unsigned short* g_ = A + (size_t)(m0 + (h)*128 + srow0) * K + (kt) + sce; \
    unsigned short* l_ = sm + (((d)*32768 + (h)*16384 + w*1024) >> 1); \
    gload_lds16(g_, l_); gload_lds16(g_ + (size_t)64 * K, l_ + 4096); } while (0)
#define STGB(d, h, kt) do { \
    const unsigned short* g_ = Bt + (size_t)(n0 + (h)*128 + srow0) * K + (kt) + sce; \
    unsigned short* l_ = sm + ((65536 + (d)*32768 + (h)*16384 + w*1024) >> 1); \
    gload_lds16(g_, l_); gload_lds16(g_ + (size_t)64 * K, l_ + 4096); } while (0)
#define ALD(regs, h, kt) do { \
    const unsigned short* g_ = A + (size_t)(m0 + (h)*128 + srow0) * K + (kt) + sce; \
    regs[0] = *(const uint4*)g_; regs[1] = *(const uint4*)(g_ + (size_t)64 * K); } while (0)
#define GBLD(dst, kt) do { \
    const float* gp_ = gLn + (kt) + sce; const float* bp_ = beLn + (kt) + sce; \
    *(float4*)&dst[0] = *(const float4*)gp_; *(float4*)&dst[4] = *(const float4*)(gp_ + 4); \
    *(float4*)&dst[8] = *(const float4*)bp_; *(float4*)&dst[12] = *(const float4*)(bp_ + 4); } while (0)
#define AWR(d, h, regs, gb) do { \
    unsigned short* l_ = sm + (((d)*32768 + (h)*16384 + w*1024 + l*16) >> 1); \
    ln_wr8(l_, regs[0], mu4[(h)*2 + 0], rs4[(h)*2 + 0], gb); \
    ln_wr8(l_ + 4096, regs[1], mu4[(h)*2 + 1], rs4[(h)*2 + 1], gb); } while (0)
#define RDA(d, base) do { _Pragma("unroll") for (int kk = 0; kk < 2; ++kk) \
    _Pragma("unroll") for (int mi = 0; mi < 4; ++mi) ra[kk][mi] = AF(d, (base) + mi, kk); } while (0)
#define RDB(d, base) do { _Pragma("unroll") for (int kk = 0; kk < 2; ++kk) \
    _Pragma("unroll") for (int ni = 0; ni < 2; ++ni) rb[kk][(base) + ni] = BFR(d, (base) + ni, kk); } while (0)
#define MQ(MO, NO) do { _Pragma("unroll") for (int kk = 0; kk < 2; ++kk) \
    _Pragma("unroll") for (int mi = 0; mi < 4; ++mi) \
    _Pragma("unroll") for (int ni = 0; ni < 2; ++ni) \
      acc[(MO) + mi][(NO) + ni] = __builtin_amdgcn_mfma_f32_16x16x32_bf16( \
          ra[kk][mi], rb[kk][(NO) + ni], acc[(MO) + mi][(NO) + ni], 0, 0, 0); } while (0)
#define BAR() __builtin_amdgcn_s_barrier()
#define WAITLGKM() asm volatile("s_waitcnt lgkmcnt(0)" ::: "memory")
#define WAITLGKM8() asm volatile("s_waitcnt lgkmcnt(8)" ::: "memory")
#define WAITVM(n) asm volatile("s_waitcnt vmcnt(" #n ")" ::: "memory")
#define PRIO1() __builtin_amdgcn_s_setprio(1)
#define PRIO0() __builtin_amdgcn_s_setprio(0)

  if (!FUSED) {
    // prologue: tile0 fully + tile1 B-halves; wait tile0 (leave 4)
    STGA(0, 0, 0); STGA(0, 1, 0); STGB(0, 0, 0); STGB(0, 1, 0);
    STGB(1, 0, 64); STGB(1, 1, 64);
    WAITVM(4); BAR();
  } else {
    // per-row LN params (4 staged rows per thread)
#pragma unroll
    for (int h = 0; h < 2; ++h)
#pragma unroll
      for (int rr = 0; rr < 2; ++rr) {
        const int row = m0 + h * 128 + srow0 + rr * 64;
        const float s1 = stats[row * 2], s2 = stats[row * 2 + 1];
        const float m = s1 * (1.0f / HID);
        mu4[h * 2 + rr] = m;
        rs4[h * 2 + rr] = rsqrtf(s2 * (1.0f / HID) - m * m + 1e-5f);
      }
    // prologue: transform-stage A(t0); glds B(t0); prefetch A(t1)+gb(t1)+B(t1)
    ALD(rA, 0, 0); GBLD(gbA, 0); ALD(rB, 1, 0);
    STGB(0, 0, 0); STGB(0, 1, 0);
    AWR(0, 0, rA, gbA);        // auto-waits drain A(t0)/gb(t0)
    AWR(0, 1, rB, gbA);
    ALD(rA, 0, 64); ALD(rB, 1, 64); GBLD(gbA, 64);
    STGB(1, 0, 64); STGB(1, 1, 64);
    WAITVM(12);                // B(t0) drained (newest 12 = t1 prefetches)
    WAITLGKM();                // commit our ds_writes
    BAR();
  }

  for (int t = 0; t < NT; t += 2) {
    const int kt1 = (t + 1) << 6;
    const int kt2 = ((t + 2 < NT) ? (t + 2) : (NT - 1)) << 6;
    const int kt3 = ((t + 3 < NT) ? (t + 3) : (NT - 1)) << 6;
    // P1: write/stage buf1-h0 <- t+1; reads A(mi0-3)+B(ni0-1) of buf0
    if (!FUSED) { RDA(0, 0); RDB(0, 0); STGA(1, 0, kt1); }
    else        { AWR(1, 0, rA, gbA); RDA(0, 0); RDB(0, 0); }
    WAITLGKM8();
    BAR(); WAITLGKM();
    PRIO1(); MQ(0, 0); PRIO0();
    BAR();
    // P2: write/stage buf1-h1 <- t+1; reads B(ni2-3)
    if (!FUSED) { RDB(0, 2); STGA(1, 1, kt1); }
    else        { AWR(1, 1, rB, gbA); RDB(0, 2); }
    BAR(); WAITLGKM();
    PRIO1(); MQ(0, 2); PRIO0();
    BAR();
    // P3: [F] prefetch A-h0(t+2)+gb(t+2); reads A(mi4-7); glds B0-h0(t+2)
    if (FUSED) { ALD(rA, 0, kt2); GBLD(gbB, kt2); }
    RDA(0, 4); STGB(0, 0, kt2);
    BAR(); WAITLGKM();
    PRIO1(); MQ(4, 2); PRIO0();
    BAR();
    // P4: [F] prefetch A-h1(t+2); glds B0-h1(t+2); wait: B(t+1) landed
    if (FUSED) { ALD(rB, 1, kt2); }
    STGB(0, 1, kt2);
    BAR();
    PRIO1(); MQ(4, 0); PRIO0();
    if (!FUSED) { WAITVM(4); } else { WAITVM(12); }
    BAR();
    // P5: write/stage buf0-h0 <- t+2; reads buf1 A(mi0-3)+B(ni0-1)
    if (!FUSED) { RDA(1, 0); RDB(1, 0); STGA(0, 0, kt2); }
    else        { AWR(0, 0, rA, gbB); RDA(1, 0); RDB(1, 0); }
    WAITLGKM8();
    BAR(); WAITLGKM();
    PRIO1(); MQ(0, 0); PRIO0();
    BAR();
    // P6: write/stage buf0-h1 <- t+2; reads B(ni2-3)
    if (!FUSED) { RDB(1, 2); STGA(0, 1, kt2); }
    else        { AWR(0, 1, rB, gbB); RDB(1, 2); }
    BAR(); WAITLGKM();
    PRIO1(); MQ(0, 2); PRIO0();
    BAR();
    // P7: [F] prefetch A-h0(t+3)+gb(t+3); reads A(mi4-7); glds B1-h0(t+3)
    if (FUSED) { ALD(rA, 0, kt3); GBLD(gbA, kt3); }
    RDA(1, 4); STGB(1, 0, kt3);
    BAR(); WAITLGKM();
    PRIO1(); MQ(4, 2); PRIO0();
    BAR();
    // P8: [F] prefetch A-h1(t+3); glds B1-h1(t+3); wait: B(t+2) landed
    if (FUSED) { ALD(rB, 1, kt3); }
    STGB(1, 1, kt3);
    BAR();
    PRIO1(); MQ(4, 0); PRIO0();
    if (!FUSED) { WAITVM(4); } else { WAITVM(12); }
    BAR();
  }

  // epilogue: drain, then C = bf16(acc + bias[col])
  WAITVM(0);
  const int wr = (w >> 2) << 7, wc = (w & 3) << 6;
  float s1s[8][4], s2s[8][4];
#pragma unroll
  for (int mi = 0; mi < 8; ++mi) {
    const int row = m0 + wr + mi * 16 + ((l >> 4) << 2);
#pragma unroll
    for (int r = 0; r < 4; ++r) { s1s[mi][r] = 0.f; s2s[mi][r] = 0.f; }
#pragma unroll
    for (int ni = 0; ni < 4; ++ni) {
      const int col = n0 + wc + ni * 16 + (l & 15);
      const float bc = bias[col];
#pragma unroll
      for (int r = 0; r < 4; ++r) {
        const float x = acc[mi][ni][r] + bc;
        C[(size_t)(row + r) * N + col] = f2bf(x);
        if (!FUSED) { s1s[mi][r] += x; s2s[mi][r] += x * x; }
      }
    }
  }
  if (!FUSED) {
#pragma unroll
    for (int mi = 0; mi < 8; ++mi)
#pragma unroll
      for (int r = 0; r < 4; ++r) {
        float s1 = s1s[mi][r], s2 = s2s[mi][r];
#pragma unroll
        for (int o = 1; o < 16; o <<= 1) {
          s1 += __shfl_xor(s1, o, 64);
          s2 += __shfl_xor(s2, o, 64);
        }
        if ((l & 15) == 0) {
          const int row = m0 + wr + mi * 16 + ((l >> 4) << 2) + r;
          atomicAdd(&stats[row * 2], s1);
          atomicAdd(&stats[row * 2 + 1], s2);
        }
      }
  }
#undef AF
#undef BFR
#undef STGA
#undef STGB
#undef ALD
#undef GBLD
#undef AWR
#undef RDA
#undef RDB
#undef MQ
#undef BAR
#undef WAITLGKM
#undef WAITLGKM8
#undef WAITVM
}

// ---- LN2 + ReLU + dot(row, Wf) + qoff broadcast -> out [B_ROWS][NQ] f32 ----
__global__ __launch_bounds__(256) void ln_final_k(
    const unsigned short* __restrict__ X, const float* __restrict__ g,
    const float* __restrict__ be, const float* __restrict__ Wh,
    const float* __restrict__ qoff, float* __restrict__ out) {
  const int w = threadIdx.x >> 6, l = threadIdx.x & 63;
  const size_t row = (size_t)blockIdx.x * 4 + w;
  const unsigned short* xr = X + row * HID;
  float v[16];
  float sum = 0.f, ss = 0.f;
#pragma unroll
  for (int c = 0; c < 4; ++c) {
    ushort4 u = *(const ushort4*)(xr + (c * 64 + l) * 4);
    float a0 = bf2f(u.x), a1 = bf2f(u.y), a2 = bf2f(u.z), a3 = bf2f(u.w);
    v[c * 4 + 0] = a0; v[c * 4 + 1] = a1; v[c * 4 + 2] = a2; v[c * 4 + 3] = a3;
    sum += a0 + a1 + a2 + a3;
    ss += a0 * a0 + a1 * a1 + a2 * a2 + a3 * a3;
  }
#pragma unroll
  for (int o = 32; o > 0; o >>= 1) {
    sum += __shfl_xor(sum, o, 64);
    ss  += __shfl_xor(ss, o, 64);
  }
  const float mu = sum * (1.f / HID);
  const float rs = rsqrtf(ss * (1.f / HID) - mu * mu + 1e-5f);
  float dot = 0.f;
#pragma unroll
  for (int c = 0; c < 4; ++c) {
    const int col = (c * 64 + l) * 4;
    float4 gg = *(const float4*)(g + col);
    float4 bb = *(const float4*)(be + col);
    float4 wf = *(const float4*)(Wh + col);
    dot += fmaxf((v[c * 4 + 0] - mu) * rs * gg.x + bb.x, 0.f) * wf.x;
    dot += fmaxf((v[c * 4 + 1] - mu) * rs * gg.y + bb.y, 0.f) * wf.y;
    dot += fmaxf((v[c * 4 + 2] - mu) * rs * gg.z + bb.z, 0.f) * wf.z;
    dot += fmaxf((v[c * 4 + 3] - mu) * rs * gg.w + bb.w, 0.f) * wf.w;
  }
#pragma unroll
  for (int o = 32; o > 0; o >>= 1) dot += __shfl_xor(dot, o, 64);
  out[row * NQ + l] = dot + qoff[l];
}

extern "C" void kernel_launch(void* const* d_in, const int* in_sizes, int n_in,
                              void* d_out, int out_size, void* d_ws, size_t ws_size,
                              hipStream_t stream) {
  const float* state  = (const float*)d_in[0];
  const float* action = (const float*)d_in[1];
  const float* W1  = (const float*)d_in[2];
  const float* b1  = (const float*)d_in[3];
  const float* g1  = (const float*)d_in[4];
  const float* be1 = (const float*)d_in[5];
  const float* W2  = (const float*)d_in[6];
  const float* b2  = (const float*)d_in[7];
  const float* g2  = (const float*)d_in[8];
  const float* be2 = (const float*)d_in[9];
  const float* Wq1 = (const float*)d_in[10];
  const float* bq1 = (const float*)d_in[11];
  const float* Wq2 = (const float*)d_in[12];
  const float* bq2 = (const float*)d_in[13];
  const float* Wh  = (const float*)d_in[14];
  const float* bh  = (const float*)d_in[15];
  float* out = (float*)d_out;

  // workspace layout (~91.6 MB)
  char* ws = (char*)d_ws;
  size_t off = 0;
  float* qoff  = (float*)(ws + off); off += 256;
  float* stats = (float*)(ws + off); off += (size_t)B_ROWS * 2 * 4;                     // 128 KB
  unsigned short* xb  = (unsigned short*)(ws + off); off += (size_t)B_ROWS * KPAD1 * 2; // 20.97 MB
  unsigned short* w1b = (unsigned short*)(ws + off); off += (size_t)HID * KPAD1 * 2;    // 1.31 MB
  unsigned short* w2b = (unsigned short*)(ws + off); off += (size_t)HID * HID * 2;      // 2.10 MB
  unsigned short* tb  = (unsigned short*)(ws + off); off += (size_t)B_ROWS * HID * 2;   // 33.55 MB
  unsigned short* tb2 = (unsigned short*)(ws + off);                                    // 33.55 MB

  (void)hipFuncSetAttribute((const void*)gemm8_k<false>, hipFuncAttributeMaxDynamicSharedMemorySize, 131072);
  (void)hipFuncSetAttribute((const void*)gemm8_k<true>, hipFuncAttributeMaxDynamicSharedMemorySize, 131072);

  (void)hipMemsetAsync(stats, 0, (size_t)B_ROWS * 2 * 4, stream);
  prep_k<<<PREP_BLOCKS, 256, 0, stream>>>(state, action, W1, W2, Wq1, bq1, Wq2, bq2,
                                          Wh, bh, xb, w1b, w2b, qoff);

  // GEMM1: raw pre-LN1 output + row stats
  gemm8_k<false><<<(B_ROWS / 256) * (HID / 256), 512, 131072, stream>>>(
      xb, w1b, b1, tb, stats, nullptr, nullptr, HID, KPAD1, KPAD1 / 64);
  // GEMM2: LN1+ReLU fused into A staging; raw pre-LN2 output
  gemm8_k<true><<<(B_ROWS / 256) * (HID / 256), 512, 131072, stream>>>(
      tb, w2b, b2, tb2, stats, g1, be1, HID, HID, HID / 64);
  ln_final_k<<<B_ROWS / 4, 256, 0, stream>>>(tb2, g2, be2, Wh, qoff, out);
}

// Round 10
// 145.351 us; speedup vs baseline: 1.0975x; 1.0975x over previous
//
#include <hip/hip_runtime.h>
#include <hip/hip_bf16.h>
#include <cstddef>

// Problem constants
#define B_ROWS 16384
#define SDIM 512
#define ADIM 64
#define KDIM 576    // SDIM + ADIM = 9 K-tiles of 64 (exact, no pad)
#define HID 1024
#define NQ 64

// prep segmentation (8-element work items, all boundaries 64-aligned)
#define SEG0_ITEMS (B_ROWS * (SDIM / 8))               // 1,048,576
#define SEG1_ITEMS (B_ROWS * (ADIM / 8))               // 131,072
#define EW_ITEMS (SEG0_ITEMS + SEG1_ITEMS)
#define EW_BLOCKS 2048
#define T1_BLOCKS ((KDIM / 32) * (HID / 32))           // 576
#define T2_BLOCKS ((HID / 32) * (HID / 32))            // 1024
#define PREP_BLOCKS (EW_BLOCKS + T1_BLOCKS + T2_BLOCKS + 1)

typedef __attribute__((ext_vector_type(8))) __bf16 bf16x8;
typedef __attribute__((ext_vector_type(4))) float f32x4;

static __device__ __forceinline__ float bf2f(unsigned short u) {
  union { unsigned int i; float f; } x; x.i = ((unsigned int)u) << 16; return x.f;
}
static __device__ __forceinline__ unsigned short f2bf(float f) {
  union { float f; unsigned int i; } x; x.f = f;
  unsigned int i = x.i + (0x7fffu + ((x.i >> 16) & 1u)); // RNE
  return (unsigned short)(i >> 16);
}

static __device__ __forceinline__ void gload_lds16(const unsigned short* g, unsigned short* l) {
  __builtin_amdgcn_global_load_lds(
      (const __attribute__((address_space(1))) void*)(const void*)g,
      (__attribute__((address_space(3))) void*)(void*)l, 16, 0, 0);
}

static __device__ __forceinline__ ushort4 cvt8lo(float4 a) {
  ushort4 o; o.x = f2bf(a.x); o.y = f2bf(a.y); o.z = f2bf(a.z); o.w = f2bf(a.w);
  return o;
}

// ---- transpose helper: W [Kin][N] f32 -> Wb [N][Kin] bf16 ----
static __device__ __forceinline__ void transpose_body(
    const float* __restrict__ W, unsigned short* __restrict__ Wb,
    int Kin, int N, int k0, int n0, unsigned short* tile) {
  const int tx = threadIdx.x & 31, ty = threadIdx.x >> 5;
#pragma unroll
  for (int i = 0; i < 32; i += 8)
    tile[(ty + i) * 33 + tx] = f2bf(W[(size_t)(k0 + ty + i) * N + n0 + tx]);
  __syncthreads();
#pragma unroll
  for (int i = 0; i < 32; i += 8)
    Wb[(size_t)(n0 + ty + i) * Kin + k0 + tx] = tile[tx * 33 + ty + i];
}

// ---- fused prep: pack_x (2-segment, grid-stride) + transposes + qoff ----
__global__ __launch_bounds__(256) void prep_k(
    const float* __restrict__ state, const float* __restrict__ action,
    const float* __restrict__ W1, const float* __restrict__ W2,
    const float* __restrict__ Wq1, const float* __restrict__ bq1,
    const float* __restrict__ Wq2, const float* __restrict__ bq2,
    const float* __restrict__ Wh, const float* __restrict__ bh,
    unsigned short* __restrict__ xb, unsigned short* __restrict__ w1b,
    unsigned short* __restrict__ w2b, float* __restrict__ qoff) {
  __shared__ unsigned short tile[32 * 33];
  const int b = blockIdx.x;
  if (b < EW_BLOCKS) {
    for (int i = b * 256 + (int)threadIdx.x; i < EW_ITEMS; i += EW_BLOCKS * 256) {
      if (i < SEG0_ITEMS) {
        // state: row = i>>6, col = (i&63)*8
        const int r = i >> 6, c = (i & 63) << 3;
        const float* sp = state + (size_t)r * SDIM + c;
        float4 a = *(const float4*)sp;
        float4 bb = *(const float4*)(sp + 4);
        unsigned short* yp = xb + (size_t)r * KDIM + c;
        *(ushort4*)yp = cvt8lo(a);
        *(ushort4*)(yp + 4) = cvt8lo(bb);
      } else {
        const int j = i - SEG0_ITEMS;
        const int r = j >> 3, ca = (j & 7) << 3;
        const float* ap = action + (size_t)r * ADIM + ca;
        float4 a = *(const float4*)ap;
        float4 bb = *(const float4*)(ap + 4);
        unsigned short* yp = xb + (size_t)r * KDIM + SDIM + ca;
        *(ushort4*)yp = cvt8lo(a);
        *(ushort4*)(yp + 4) = cvt8lo(bb);
      }
    }
  } else if (b < EW_BLOCKS + T1_BLOCKS) {
    const int t = b - EW_BLOCKS;
    transpose_body(W1, w1b, KDIM, HID, (t / 32) * 32, (t % 32) * 32, tile);
  } else if (b < EW_BLOCKS + T1_BLOCKS + T2_BLOCKS) {
    const int t = b - EW_BLOCKS - T1_BLOCKS;
    transpose_body(W2, w2b, HID, HID, (t / 32) * 32, (t % 32) * 32, tile);
  } else {
    const int q = threadIdx.x;
    if (q < NQ) {
      const float tau = ((float)q + 0.5f) * (1.0f / (float)NQ);
      float t1[64];
#pragma unroll
      for (int k = 0; k < 64; ++k) t1[k] = fmaxf(fmaf(tau, Wq1[k], bq1[k]), 0.f);
      float acc = bh[0];
#pragma unroll 1
      for (int j = 0; j < 64; ++j) {
        float t2 = bq2[j];
#pragma unroll
        for (int k = 0; k < 64; ++k) t2 = fmaf(t1[k], Wq2[k * 64 + j], t2);
        acc = fmaf(t2, Wh[HID + j], acc);
      }
      qoff[q] = acc;
    }
  }
}

// ============================================================================
// m97-structure 128x128 bf16 GEMM (round-1 verified kernel + chunked XCD
// swizzle): C[m][n] = bf16( A@Bt^T + bias[n] ).
// A: [M][K] bf16, Bt: [N][K] bf16. 256 threads = 4 waves (2x2, 64x64 each).
// 32 KB static LDS, single-buffered, 2 barriers per K-step -> 4-5 blocks/CU
// resident: cross-block wave overlap (m114) covers the barrier drains.
// Chunked swizzle: XCD x gets a contiguous bid range -> contiguous bm range;
// A-panels per XCD (16 x 144-256KB) fit the 4MB L2, B stays hot -> kills
// r1's 133MB over-fetch.
// ============================================================================
__global__ __launch_bounds__(256) void gemm97_k(
    const unsigned short* __restrict__ A, const unsigned short* __restrict__ Bt,
    const float* __restrict__ bias, unsigned short* __restrict__ C,
    int N, int K) {
  __shared__ unsigned short As[128 * 64];
  __shared__ unsigned short Bs[128 * 64];
  const int tid = threadIdx.x;
  const int w = tid >> 6, l = tid & 63;

  // chunked XCD swizzle (gridDim.x % 8 == 0)
  const int cpx = (int)gridDim.x >> 3;
  int bid = (int)blockIdx.x;
  bid = (bid & 7) * cpx + (bid >> 3);
  const int nb = N >> 7;
  const int bm = bid / nb, bn = bid % nb;
  const int m0 = bm << 7, n0 = bn << 7;
  const int wm = (w >> 1) << 6, wn = (w & 1) << 6; // 2x2 wave grid, 64x64 each
  const int srow = l >> 3;         // staging row within 8-row chunk
  const int scol = (l & 7) << 3;   // staging col (bf16 elems), 8 elems = 16B

  f32x4 acc[4][4] = {};

  const unsigned short* ga0 = A + (size_t)(m0 + w * 8 + srow) * K + scol;
  const unsigned short* gb0 = Bt + (size_t)(n0 + w * 8 + srow) * K + scol;
  unsigned short* la0 = &As[(w * 8) * 64];
  unsigned short* lb0 = &Bs[(w * 8) * 64];

  for (int kt = 0; kt < K; kt += 64) {
#pragma unroll
    for (int i = 0; i < 4; ++i) {
      gload_lds16(ga0 + (size_t)(i * 32) * K + kt, la0 + i * 32 * 64);
      gload_lds16(gb0 + (size_t)(i * 32) * K + kt, lb0 + i * 32 * 64);
    }
    asm volatile("s_waitcnt vmcnt(0)" ::: "memory");
    __syncthreads();
#pragma unroll
    for (int kk = 0; kk < 64; kk += 32) {
      bf16x8 af[4], bfr[4];
#pragma unroll
      for (int i = 0; i < 4; ++i) {
        af[i]  = *(const bf16x8*)&As[(wm + i * 16 + (l & 15)) * 64 + kk + (l >> 4) * 8];
        bfr[i] = *(const bf16x8*)&Bs[(wn + i * 16 + (l & 15)) * 64 + kk + (l >> 4) * 8];
      }
#pragma unroll
      for (int i = 0; i < 4; ++i)
#pragma unroll
        for (int j = 0; j < 4; ++j)
          acc[i][j] = __builtin_amdgcn_mfma_f32_16x16x32_bf16(af[i], bfr[j], acc[i][j], 0, 0, 0);
    }
    __syncthreads();
  }
  // epilogue: C = bf16(acc + bias[col]); C/D layout: col=lane&15, row=(lane>>4)*4+r
#pragma unroll
  for (int i = 0; i < 4; ++i) {
    const int row = m0 + wm + i * 16 + (l >> 4) * 4;
#pragma unroll
    for (int j = 0; j < 4; ++j) {
      const int col = n0 + wn + j * 16 + (l & 15);
      const float bc = bias[col];
#pragma unroll
      for (int r = 0; r < 4; ++r)
        C[(size_t)(row + r) * N + col] = f2bf(acc[i][j][r] + bc);
    }
  }
}

// ---- LayerNorm + ReLU -> bf16, one wave per row of 1024 ----
__global__ __launch_bounds__(256) void ln_relu_k(
    const unsigned short* __restrict__ X, const float* __restrict__ g,
    const float* __restrict__ be, unsigned short* __restrict__ Y) {
  const int w = threadIdx.x >> 6, l = threadIdx.x & 63;
  const size_t row = (size_t)blockIdx.x * 4 + w;
  const unsigned short* xr = X + row * HID;
  float v[16];
  float sum = 0.f, ss = 0.f;
#pragma unroll
  for (int c = 0; c < 4; ++c) {
    ushort4 u = *(const ushort4*)(xr + (c * 64 + l) * 4);
    float a0 = bf2f(u.x), a1 = bf2f(u.y), a2 = bf2f(u.z), a3 = bf2f(u.w);
    v[c * 4 + 0] = a0; v[c * 4 + 1] = a1; v[c * 4 + 2] = a2; v[c * 4 + 3] = a3;
    sum += a0 + a1 + a2 + a3;
    ss += a0 * a0 + a1 * a1 + a2 * a2 + a3 * a3;
  }
#pragma unroll
  for (int o = 32; o > 0; o >>= 1) {
    sum += __shfl_xor(sum, o, 64);
    ss  += __shfl_xor(ss, o, 64);
  }
  const float mu = sum * (1.f / HID);
  const float rs = rsqrtf(ss * (1.f / HID) - mu * mu + 1e-5f);
  unsigned short* yr = Y + row * HID;
#pragma unroll
  for (int c = 0; c < 4; ++c) {
    const int col = (c * 64 + l) * 4;
    float4 gg = *(const float4*)(g + col);
    float4 bb = *(const float4*)(be + col);
    ushort4 o4;
    o4.x = f2bf(fmaxf((v[c * 4 + 0] - mu) * rs * gg.x + bb.x, 0.f));
    o4.y = f2bf(fmaxf((v[c * 4 + 1] - mu) * rs * gg.y + bb.y, 0.f));
    o4.z = f2bf(fmaxf((v[c * 4 + 2] - mu) * rs * gg.z + bb.z, 0.f));
    o4.w = f2bf(fmaxf((v[c * 4 + 3] - mu) * rs * gg.w + bb.w, 0.f));
    *(ushort4*)(yr + col) = o4;
  }
}

// ---- LN2 + ReLU + dot(row, Wf) + qoff broadcast -> out [B_ROWS][NQ] f32 ----
__global__ __launch_bounds__(256) void ln_final_k(
    const unsigned short* __restrict__ X, const float* __restrict__ g,
    const float* __restrict__ be, const float* __restrict__ Wh,
    const float* __restrict__ qoff, float* __restrict__ out) {
  const int w = threadIdx.x >> 6, l = threadIdx.x & 63;
  const size_t row = (size_t)blockIdx.x * 4 + w;
  const unsigned short* xr = X + row * HID;
  float v[16];
  float sum = 0.f, ss = 0.f;
#pragma unroll
  for (int c = 0; c < 4; ++c) {
    ushort4 u = *(const ushort4*)(xr + (c * 64 + l) * 4);
    float a0 = bf2f(u.x), a1 = bf2f(u.y), a2 = bf2f(u.z), a3 = bf2f(u.w);
    v[c * 4 + 0] = a0; v[c * 4 + 1] = a1; v[c * 4 + 2] = a2; v[c * 4 + 3] = a3;
    sum += a0 + a1 + a2 + a3;
    ss += a0 * a0 + a1 * a1 + a2 * a2 + a3 * a3;
  }
#pragma unroll
  for (int o = 32; o > 0; o >>= 1) {
    sum += __shfl_xor(sum, o, 64);
    ss  += __shfl_xor(ss, o, 64);
  }
  const float mu = sum * (1.f / HID);
  const float rs = rsqrtf(ss * (1.f / HID) - mu * mu + 1e-5f);
  float dot = 0.f;
#pragma unroll
  for (int c = 0; c < 4; ++c) {
    const int col = (c * 64 + l) * 4;
    float4 gg = *(const float4*)(g + col);
    float4 bb = *(const float4*)(be + col);
    float4 wf = *(const float4*)(Wh + col); // Wf = Wh[:HID]
    dot += fmaxf((v[c * 4 + 0] - mu) * rs * gg.x + bb.x, 0.f) * wf.x;
    dot += fmaxf((v[c * 4 + 1] - mu) * rs * gg.y + bb.y, 0.f) * wf.y;
    dot += fmaxf((v[c * 4 + 2] - mu) * rs * gg.z + bb.z, 0.f) * wf.z;
    dot += fmaxf((v[c * 4 + 3] - mu) * rs * gg.w + bb.w, 0.f) * wf.w;
  }
#pragma unroll
  for (int o = 32; o > 0; o >>= 1) dot += __shfl_xor(dot, o, 64);
  out[row * NQ + l] = dot + qoff[l];
}

extern "C" void kernel_launch(void* const* d_in, const int* in_sizes, int n_in,
                              void* d_out, int out_size, void* d_ws, size_t ws_size,
                              hipStream_t stream) {
  const float* state  = (const float*)d_in[0];
  const float* action = (const float*)d_in[1];
  const float* W1  = (const float*)d_in[2];
  const float* b1  = (const float*)d_in[3];
  const float* g1  = (const float*)d_in[4];
  const float* be1 = (const float*)d_in[5];
  const float* W2  = (const float*)d_in[6];
  const float* b2  = (const float*)d_in[7];
  const float* g2  = (const float*)d_in[8];
  const float* be2 = (const float*)d_in[9];
  const float* Wq1 = (const float*)d_in[10];
  const float* bq1 = (const float*)d_in[11];
  const float* Wq2 = (const float*)d_in[12];
  const float* bq2 = (const float*)d_in[13];
  const float* Wh  = (const float*)d_in[14];
  const float* bh  = (const float*)d_in[15];
  float* out = (float*)d_out;

  // workspace layout (~90 MB)
  char* ws = (char*)d_ws;
  size_t off = 0;
  float* qoff = (float*)(ws + off); off += 256;
  unsigned short* xb  = (unsigned short*)(ws + off); off += (size_t)B_ROWS * KDIM * 2; // 18.87 MB
  unsigned short* w1b = (unsigned short*)(ws + off); off += (size_t)HID * KDIM * 2;    // 1.18 MB
  unsigned short* w2b = (unsigned short*)(ws + off); off += (size_t)HID * HID * 2;     // 2.10 MB
  unsigned short* h1b = (unsigned short*)(ws + off); off += (size_t)B_ROWS * HID * 2;  // 33.55 MB
  unsigned short* tb  = (unsigned short*)(ws + off);                                   // 33.55 MB

  prep_k<<<PREP_BLOCKS, 256, 0, stream>>>(state, action, W1, W2, Wq1, bq1, Wq2, bq2,
                                          Wh, bh, xb, w1b, w2b, qoff);

  gemm97_k<<<(B_ROWS / 128) * (HID / 128), 256, 0, stream>>>(xb, w1b, b1, tb, HID, KDIM);
  ln_relu_k<<<B_ROWS / 4, 256, 0, stream>>>(tb, g1, be1, h1b);
  gemm97_k<<<(B_ROWS / 128) * (HID / 128), 256, 0, stream>>>(h1b, w2b, b2, tb, HID, HID);
  ln_final_k<<<B_ROWS / 4, 256, 0, stream>>>(tb, g2, be2, Wh, qoff, out);
}

// Round 11
// 131.187 us; speedup vs baseline: 1.2160x; 1.1080x over previous
//
#include <hip/hip_runtime.h>
#include <hip/hip_bf16.h>
#include <cstddef>

// Problem constants
#define B_ROWS 16384
#define SDIM 512
#define ADIM 64
#define KDIM 576    // SDIM + ADIM = 9 K-tiles of 64 (exact)
#define HID 1024
#define NQ 64

// prep segmentation (8-element work items, all boundaries 64-aligned)
#define SEG0_ITEMS (B_ROWS * (SDIM / 8))
#define SEG1_ITEMS (B_ROWS * (ADIM / 8))
#define EW_ITEMS (SEG0_ITEMS + SEG1_ITEMS)
#define EW_BLOCKS 2048
#define T1_BLOCKS ((KDIM / 32) * (HID / 32))
#define T2_BLOCKS ((HID / 32) * (HID / 32))
#define PREP_BLOCKS (EW_BLOCKS + T1_BLOCKS + T2_BLOCKS + 1)

typedef __attribute__((ext_vector_type(8))) __bf16 bf16x8;
typedef __attribute__((ext_vector_type(4))) float f32x4;

static __device__ __forceinline__ float bf2f(unsigned short u) {
  union { unsigned int i; float f; } x; x.i = ((unsigned int)u) << 16; return x.f;
}
static __device__ __forceinline__ unsigned short f2bf(float f) {
  union { float f; unsigned int i; } x; x.f = f;
  unsigned int i = x.i + (0x7fffu + ((x.i >> 16) & 1u)); // RNE
  return (unsigned short)(i >> 16);
}

static __device__ __forceinline__ void gload_lds16(const unsigned short* g, unsigned short* l) {
  __builtin_amdgcn_global_load_lds(
      (const __attribute__((address_space(1))) void*)(const void*)g,
      (__attribute__((address_space(3))) void*)(void*)l, 16, 0, 0);
}

static __device__ __forceinline__ ushort4 cvt8lo(float4 a) {
  ushort4 o; o.x = f2bf(a.x); o.y = f2bf(a.y); o.z = f2bf(a.z); o.w = f2bf(a.w);
  return o;
}

// ---- transpose helper: W [Kin][N] f32 -> Wb [N][Kin] bf16 ----
static __device__ __forceinline__ void transpose_body(
    const float* __restrict__ W, unsigned short* __restrict__ Wb,
    int Kin, int N, int k0, int n0, unsigned short* tile) {
  const int tx = threadIdx.x & 31, ty = threadIdx.x >> 5;
#pragma unroll
  for (int i = 0; i < 32; i += 8)
    tile[(ty + i) * 33 + tx] = f2bf(W[(size_t)(k0 + ty + i) * N + n0 + tx]);
  __syncthreads();
#pragma unroll
  for (int i = 0; i < 32; i += 8)
    Wb[(size_t)(n0 + ty + i) * Kin + k0 + tx] = tile[tx * 33 + ty + i];
}

// ---- fused prep: pack_x (2-segment, grid-stride) + transposes + qoff ----
__global__ __launch_bounds__(256) void prep_k(
    const float* __restrict__ state, const float* __restrict__ action,
    const float* __restrict__ W1, const float* __restrict__ W2,
    const float* __restrict__ Wq1, const float* __restrict__ bq1,
    const float* __restrict__ Wq2, const float* __restrict__ bq2,
    const float* __restrict__ Wh, const float* __restrict__ bh,
    unsigned short* __restrict__ xb, unsigned short* __restrict__ w1b,
    unsigned short* __restrict__ w2b, float* __restrict__ qoff) {
  __shared__ unsigned short tile[32 * 33];
  const int b = blockIdx.x;
  if (b < EW_BLOCKS) {
    for (int i = b * 256 + (int)threadIdx.x; i < EW_ITEMS; i += EW_BLOCKS * 256) {
      if (i < SEG0_ITEMS) {
        const int r = i >> 6, c = (i & 63) << 3;
        const float* sp = state + (size_t)r * SDIM + c;
        float4 a = *(const float4*)sp;
        float4 bb = *(const float4*)(sp + 4);
        unsigned short* yp = xb + (size_t)r * KDIM + c;
        *(ushort4*)yp = cvt8lo(a);
        *(ushort4*)(yp + 4) = cvt8lo(bb);
      } else {
        const int j = i - SEG0_ITEMS;
        const int r = j >> 3, ca = (j & 7) << 3;
        const float* ap = action + (size_t)r * ADIM + ca;
        float4 a = *(const float4*)ap;
        float4 bb = *(const float4*)(ap + 4);
        unsigned short* yp = xb + (size_t)r * KDIM + SDIM + ca;
        *(ushort4*)yp = cvt8lo(a);
        *(ushort4*)(yp + 4) = cvt8lo(bb);
      }
    }
  } else if (b < EW_BLOCKS + T1_BLOCKS) {
    const int t = b - EW_BLOCKS;
    transpose_body(W1, w1b, KDIM, HID, (t / 32) * 32, (t % 32) * 32, tile);
  } else if (b < EW_BLOCKS + T1_BLOCKS + T2_BLOCKS) {
    const int t = b - EW_BLOCKS - T1_BLOCKS;
    transpose_body(W2, w2b, HID, HID, (t / 32) * 32, (t % 32) * 32, tile);
  } else {
    const int q = threadIdx.x;
    if (q < NQ) {
      const float tau = ((float)q + 0.5f) * (1.0f / (float)NQ);
      float t1[64];
#pragma unroll
      for (int k = 0; k < 64; ++k) t1[k] = fmaxf(fmaf(tau, Wq1[k], bq1[k]), 0.f);
      float acc = bh[0];
#pragma unroll 1
      for (int j = 0; j < 64; ++j) {
        float t2 = bq2[j];
#pragma unroll
        for (int k = 0; k < 64; ++k) t2 = fmaf(t1[k], Wq2[k * 64 + j], t2);
        acc = fmaf(t2, Wh[HID + j], acc);
      }
      qoff[q] = acc;
    }
  }
}

// ============================================================================
// Row-stripe fused GEMM+LN kernel. Block = 64 rows x ALL 1024 out-cols.
// Grid 256 (1/CU), 512 threads = 8 waves; wave w owns cols w*128..w*128+127.
// acc[4][8] f32x4 = 128 VGPR. Per K-tile(64): stage A(64xK-tile, 8 KB) +
// B(1024xK-tile, 128 KB) via global_load_lds with r5's st_16x32 swizzle
// (identical tile geometry to the measured r5 kernel); 2 barriers; 64 MFMA.
// Epilogue: x = acc+bias; deterministic cross-wave LDS tree-reduce for
// row mean/var; LN+ReLU applied to f32 accs.
//  FINAL=false: write bf16 h to Hout.
//  FINAL=true : row-dot with Wf (=Wh[:1024]) + qoff broadcast -> f32 Qout.
// ============================================================================
template <bool FINAL>
__global__ __launch_bounds__(512, 2) void fused_k(
    const unsigned short* __restrict__ A,   // [M][K] bf16
    const unsigned short* __restrict__ Bt,  // [1024][K] bf16 (W transposed)
    const float* __restrict__ bias,         // [1024]
    const float* __restrict__ g,            // [1024]
    const float* __restrict__ be,           // [1024]
    const float* __restrict__ Wh,           // Wf = Wh[:1024]   (FINAL)
    const float* __restrict__ qoff,         // [64]             (FINAL)
    unsigned short* __restrict__ Hout,      // bf16 [M][1024]   (!FINAL)
    float* __restrict__ Qout,               // f32  [M][64]     (FINAL)
    int K, int NT) {
  extern __shared__ unsigned short sm[];    // A-tile 8 KB @0, B-tile 128 KB @8192
  __shared__ float part[8][64][2];          // per-wave row partials
  __shared__ float murs[64][2];
  __shared__ float dotf[64];
  __shared__ float qof[64];

  const int tid = threadIdx.x;
  const int w = tid >> 6, l = tid & 63;
  const int r0 = (int)blockIdx.x * 64;

  // staging mapping (r5-verified): linear LDS slot w*1024 + lane*16 bytes
  // within an 8 KB chunk covers rows w*8+(l>>3); source col inverse-swizzled.
  const int srow0 = w * 8 + (l >> 3);                         // 0..63
  const int sce = ((((l & 7) << 4) ^ ((srow0 & 4) << 3)) >> 1); // elem offset
  // fragment-read constants (byte offsets, st_16x32 swizzle)
  const int lr = (l & 15) << 7;                               // row*128B
  const int cSw = (((l >> 4) << 4) ^ ((l & 4) << 3));         // swizzled col

  f32x4 acc[4][8] = {};

#define AF(mi, kk) (*(const bf16x8*)(sm + (((mi)*2048 + lr + cSw + ((kk) << 6)) >> 1)))
#define BFW(ni, kk) (*(const bf16x8*)(sm + ((8192 + w*16384 + (ni)*2048 + lr + cSw + ((kk) << 6)) >> 1)))

  for (int t = 0; t < NT; ++t) {
    const int kt = t << 6;
    // stage A-tile: 64 rows x 64 cols = 8 KB, 1 gload/thread
    gload_lds16(A + (size_t)(r0 + srow0) * K + kt + sce, sm + ((w * 1024) >> 1));
    // stage B-tile: 1024 rows x 64 cols = 128 KB, 8 chunks of 128 rows
#pragma unroll
    for (int c = 0; c < 8; ++c) {
      const unsigned short* g_ = Bt + (size_t)(c * 128 + srow0) * K + kt + sce;
      unsigned short* l_ = sm + ((8192 + c * 16384 + w * 1024) >> 1);
      gload_lds16(g_, l_);
      gload_lds16(g_ + (size_t)64 * K, l_ + 4096);
    }
    asm volatile("s_waitcnt vmcnt(0)" ::: "memory");
    __syncthreads();
#pragma unroll
    for (int kk = 0; kk < 2; ++kk) {
      bf16x8 af[4], bfr[8];
#pragma unroll
      for (int mi = 0; mi < 4; ++mi) af[mi] = AF(mi, kk);
#pragma unroll
      for (int ni = 0; ni < 8; ++ni) bfr[ni] = BFW(ni, kk);
      __builtin_amdgcn_s_setprio(1);
#pragma unroll
      for (int mi = 0; mi < 4; ++mi)
#pragma unroll
        for (int ni = 0; ni < 8; ++ni)
          acc[mi][ni] = __builtin_amdgcn_mfma_f32_16x16x32_bf16(af[mi], bfr[ni], acc[mi][ni], 0, 0, 0);
      __builtin_amdgcn_s_setprio(0);
    }
    __syncthreads();
  }

  // ---------------- epilogue ----------------
  // cols owned: col(ni) = w*128 + ni*16 + (l&15); rows: mi*16 + (l>>4)*4 + rr
  float bcol[8], gcol[8], becol[8];
#pragma unroll
  for (int ni = 0; ni < 8; ++ni) {
    const int col = w * 128 + ni * 16 + (l & 15);
    bcol[ni] = bias[col];
    gcol[ni] = g[col];
    becol[ni] = be[col];
  }
  // per-wave row partial sums (deterministic)
#pragma unroll
  for (int mi = 0; mi < 4; ++mi)
#pragma unroll
    for (int rr = 0; rr < 4; ++rr) {
      float s1 = 0.f, s2 = 0.f;
#pragma unroll
      for (int ni = 0; ni < 8; ++ni) {
        const float x = acc[mi][ni][rr] + bcol[ni];
        s1 += x; s2 += x * x;
      }
#pragma unroll
      for (int o = 1; o < 16; o <<= 1) {
        s1 += __shfl_xor(s1, o, 64);
        s2 += __shfl_xor(s2, o, 64);
      }
      if ((l & 15) == 0) {
        const int row = mi * 16 + (l >> 4) * 4 + rr;
        part[w][row][0] = s1;
        part[w][row][1] = s2;
      }
    }
  __syncthreads();
  if (tid < 64) {
    float s1 = 0.f, s2 = 0.f;
#pragma unroll
    for (int ww = 0; ww < 8; ++ww) { s1 += part[ww][tid][0]; s2 += part[ww][tid][1]; }
    const float mu = s1 * (1.0f / HID);
    murs[tid][0] = mu;
    murs[tid][1] = rsqrtf(s2 * (1.0f / HID) - mu * mu + 1e-5f);
    if (FINAL) qof[tid] = qoff[tid];
  }
  __syncthreads();

  if (!FINAL) {
#pragma unroll
    for (int mi = 0; mi < 4; ++mi)
#pragma unroll
      for (int rr = 0; rr < 4; ++rr) {
        const int row = mi * 16 + (l >> 4) * 4 + rr;
        const float mu = murs[row][0], rs = murs[row][1];
        unsigned short* hp = Hout + (size_t)(r0 + row) * HID + w * 128 + (l & 15);
#pragma unroll
        for (int ni = 0; ni < 8; ++ni) {
          const float x = acc[mi][ni][rr] + bcol[ni];
          hp[ni * 16] = f2bf(fmaxf((x - mu) * rs * gcol[ni] + becol[ni], 0.f));
        }
      }
  } else {
    float wf[8];
#pragma unroll
    for (int ni = 0; ni < 8; ++ni) wf[ni] = Wh[w * 128 + ni * 16 + (l & 15)];
#pragma unroll
    for (int mi = 0; mi < 4; ++mi)
#pragma unroll
      for (int rr = 0; rr < 4; ++rr) {
        const int row = mi * 16 + (l >> 4) * 4 + rr;
        const float mu = murs[row][0], rs = murs[row][1];
        float dp = 0.f;
#pragma unroll
        for (int ni = 0; ni < 8; ++ni) {
          const float x = acc[mi][ni][rr] + bcol[ni];
          dp += fmaxf((x - mu) * rs * gcol[ni] + becol[ni], 0.f) * wf[ni];
        }
#pragma unroll
        for (int o = 1; o < 16; o <<= 1) dp += __shfl_xor(dp, o, 64);
        if ((l & 15) == 0) part[w][row][0] = dp;
      }
    __syncthreads();
    if (tid < 64) {
      float d = 0.f;
#pragma unroll
      for (int ww = 0; ww < 8; ++ww) d += part[ww][tid][0];
      dotf[tid] = d;
    }
    __syncthreads();
#pragma unroll
    for (int it = 0; it < 8; ++it) {
      const int idx = tid + it * 512;          // 0..4095
      const int row = idx >> 6, q = idx & 63;
      Qout[(size_t)(r0 + row) * NQ + q] = dotf[row] + qof[q];
    }
  }
#undef AF
#undef BFW
}

extern "C" void kernel_launch(void* const* d_in, const int* in_sizes, int n_in,
                              void* d_out, int out_size, void* d_ws, size_t ws_size,
                              hipStream_t stream) {
  const float* state  = (const float*)d_in[0];
  const float* action = (const float*)d_in[1];
  const float* W1  = (const float*)d_in[2];
  const float* b1  = (const float*)d_in[3];
  const float* g1  = (const float*)d_in[4];
  const float* be1 = (const float*)d_in[5];
  const float* W2  = (const float*)d_in[6];
  const float* b2  = (const float*)d_in[7];
  const float* g2  = (const float*)d_in[8];
  const float* be2 = (const float*)d_in[9];
  const float* Wq1 = (const float*)d_in[10];
  const float* bq1 = (const float*)d_in[11];
  const float* Wq2 = (const float*)d_in[12];
  const float* bq2 = (const float*)d_in[13];
  const float* Wh  = (const float*)d_in[14];
  const float* bh  = (const float*)d_in[15];
  float* out = (float*)d_out;

  // workspace (~56 MB)
  char* ws = (char*)d_ws;
  size_t off = 0;
  float* qoff = (float*)(ws + off); off += 256;
  unsigned short* xb  = (unsigned short*)(ws + off); off += (size_t)B_ROWS * KDIM * 2; // 18.87 MB
  unsigned short* w1b = (unsigned short*)(ws + off); off += (size_t)HID * KDIM * 2;    // 1.18 MB
  unsigned short* w2b = (unsigned short*)(ws + off); off += (size_t)HID * HID * 2;     // 2.10 MB
  unsigned short* h1b = (unsigned short*)(ws + off);                                   // 33.55 MB

  const int ldsBytes = 8192 + 131072;  // A-tile + B-tile
  (void)hipFuncSetAttribute((const void*)fused_k<false>, hipFuncAttributeMaxDynamicSharedMemorySize, ldsBytes);
  (void)hipFuncSetAttribute((const void*)fused_k<true>, hipFuncAttributeMaxDynamicSharedMemorySize, ldsBytes);

  prep_k<<<PREP_BLOCKS, 256, 0, stream>>>(state, action, W1, W2, Wq1, bq1, Wq2, bq2,
                                          Wh, bh, xb, w1b, w2b, qoff);

  // layer 1: h1 = relu(LN(x@W1 + b1))  -> h1b (bf16)
  fused_k<false><<<B_ROWS / 64, 512, ldsBytes, stream>>>(
      xb, w1b, b1, g1, be1, nullptr, nullptr, h1b, nullptr, KDIM, KDIM / 64);
  // layer 2 + head: out = relu(LN(h1@W2 + b2)) @ Wf + qoff
  fused_k<true><<<B_ROWS / 64, 512, ldsBytes, stream>>>(
      h1b, w2b, b2, g2, be2, Wh, qoff, nullptr, out, HID, HID / 64);
}

// Round 12
// 108.383 us; speedup vs baseline: 1.4718x; 1.2104x over previous
//
#include <hip/hip_runtime.h>
#include <hip/hip_bf16.h>
#include <cstddef>

// Problem constants
#define B_ROWS 16384
#define SDIM 512
#define ADIM 64
#define KDIM 576    // SDIM + ADIM = 9 K-tiles of 64 (exact)
#define HID 1024
#define NQ 64

// prep segmentation (8-element work items, all boundaries 64-aligned)
#define SEG0_ITEMS (B_ROWS * (SDIM / 8))
#define SEG1_ITEMS (B_ROWS * (ADIM / 8))
#define EW_ITEMS (SEG0_ITEMS + SEG1_ITEMS)
#define EW_BLOCKS 2048
#define T1_BLOCKS ((KDIM / 32) * (HID / 32))
#define T2_BLOCKS ((HID / 32) * (HID / 32))
#define PREP_BLOCKS (EW_BLOCKS + T1_BLOCKS + T2_BLOCKS + 1)

#define FK_LDS (16384 + 131072)   // A double-buffer (2x8KB) + B (8 waves x 16KB)

typedef __attribute__((ext_vector_type(8))) __bf16 bf16x8;
typedef __attribute__((ext_vector_type(4))) float f32x4;

static __device__ __forceinline__ float bf2f(unsigned short u) {
  union { unsigned int i; float f; } x; x.i = ((unsigned int)u) << 16; return x.f;
}
static __device__ __forceinline__ unsigned short f2bf(float f) {
  union { float f; unsigned int i; } x; x.f = f;
  unsigned int i = x.i + (0x7fffu + ((x.i >> 16) & 1u)); // RNE
  return (unsigned short)(i >> 16);
}

static __device__ __forceinline__ void gload_lds16(const unsigned short* g, unsigned short* l) {
  __builtin_amdgcn_global_load_lds(
      (const __attribute__((address_space(1))) void*)(const void*)g,
      (__attribute__((address_space(3))) void*)(void*)l, 16, 0, 0);
}

static __device__ __forceinline__ ushort4 cvt8lo(float4 a) {
  ushort4 o; o.x = f2bf(a.x); o.y = f2bf(a.y); o.z = f2bf(a.z); o.w = f2bf(a.w);
  return o;
}

// ---- transpose helper: W [Kin][N] f32 -> Wb [N][Kin] bf16 ----
static __device__ __forceinline__ void transpose_body(
    const float* __restrict__ W, unsigned short* __restrict__ Wb,
    int Kin, int N, int k0, int n0, unsigned short* tile) {
  const int tx = threadIdx.x & 31, ty = threadIdx.x >> 5;
#pragma unroll
  for (int i = 0; i < 32; i += 8)
    tile[(ty + i) * 33 + tx] = f2bf(W[(size_t)(k0 + ty + i) * N + n0 + tx]);
  __syncthreads();
#pragma unroll
  for (int i = 0; i < 32; i += 8)
    Wb[(size_t)(n0 + ty + i) * Kin + k0 + tx] = tile[tx * 33 + ty + i];
}

// ---- fused prep: pack_x (2-segment, grid-stride) + transposes + qoff ----
__global__ __launch_bounds__(256) void prep_k(
    const float* __restrict__ state, const float* __restrict__ action,
    const float* __restrict__ W1, const float* __restrict__ W2,
    const float* __restrict__ Wq1, const float* __restrict__ bq1,
    const float* __restrict__ Wq2, const float* __restrict__ bq2,
    const float* __restrict__ Wh, const float* __restrict__ bh,
    unsigned short* __restrict__ xb, unsigned short* __restrict__ w1b,
    unsigned short* __restrict__ w2b, float* __restrict__ qoff) {
  __shared__ unsigned short tile[32 * 33];
  const int b = blockIdx.x;
  if (b < EW_BLOCKS) {
    for (int i = b * 256 + (int)threadIdx.x; i < EW_ITEMS; i += EW_BLOCKS * 256) {
      if (i < SEG0_ITEMS) {
        const int r = i >> 6, c = (i & 63) << 3;
        const float* sp = state + (size_t)r * SDIM + c;
        float4 a = *(const float4*)sp;
        float4 bb = *(const float4*)(sp + 4);
        unsigned short* yp = xb + (size_t)r * KDIM + c;
        *(ushort4*)yp = cvt8lo(a);
        *(ushort4*)(yp + 4) = cvt8lo(bb);
      } else {
        const int j = i - SEG0_ITEMS;
        const int r = j >> 3, ca = (j & 7) << 3;
        const float* ap = action + (size_t)r * ADIM + ca;
        float4 a = *(const float4*)ap;
        float4 bb = *(const float4*)(ap + 4);
        unsigned short* yp = xb + (size_t)r * KDIM + SDIM + ca;
        *(ushort4*)yp = cvt8lo(a);
        *(ushort4*)(yp + 4) = cvt8lo(bb);
      }
    }
  } else if (b < EW_BLOCKS + T1_BLOCKS) {
    const int t = b - EW_BLOCKS;
    transpose_body(W1, w1b, KDIM, HID, (t / 32) * 32, (t % 32) * 32, tile);
  } else if (b < EW_BLOCKS + T1_BLOCKS + T2_BLOCKS) {
    const int t = b - EW_BLOCKS - T1_BLOCKS;
    transpose_body(W2, w2b, HID, HID, (t / 32) * 32, (t % 32) * 32, tile);
  } else {
    const int q = threadIdx.x;
    if (q < NQ) {
      const float tau = ((float)q + 0.5f) * (1.0f / (float)NQ);
      float t1[64];
#pragma unroll
      for (int k = 0; k < 64; ++k) t1[k] = fmaxf(fmaf(tau, Wq1[k], bq1[k]), 0.f);
      float acc = bh[0];
#pragma unroll 1
      for (int j = 0; j < 64; ++j) {
        float t2 = bq2[j];
#pragma unroll
        for (int k = 0; k < 64; ++k) t2 = fmaf(t1[k], Wq2[k * 64 + j], t2);
        acc = fmaf(t2, Wh[HID + j], acc);
      }
      qoff[q] = acc;
    }
  }
}

// ============================================================================
// Pipelined row-stripe fused GEMM+LN. Block = 64 rows x ALL 1024 out-cols.
// Grid 256, 512 threads = 8 waves; wave w owns out-cols w*128..w*128+127,
// hence B-chunk w (W rows w*128..+127) is WAVE-PRIVATE: staged and read only
// by wave w -> no barriers for B, per-wave counted vmcnt only.
// A (64xKtile, 8 KB) is cross-wave: double-buffered, 1 barrier/tile.
// LDS: abuf0@0, abuf1@8192, B@16384+w*16384 (147456 B dyn + ~5 KB static).
// Per-tile: vmcnt(1|0) -> frags kk0 -> MFMA -> frags kk1 -> lgkm(0) ->
// issue B(t+1) -> MFMA -> vmcnt(16) [drain own A(t+1) write] -> barrier ->
// issue A(t+2) into just-read abuf (post-barrier => no WAR race).
// K-order staggered per block ((t+bid)%NT) to decorrelate L2 W-line traffic.
// Epilogue (r11-verified): cross-wave LDS tree-reduce for row mean/var,
// LN+ReLU on f32 accs; FINAL adds rank-1 Wf-dot + qoff.
// ============================================================================
template <bool FINAL>
__global__ __launch_bounds__(512, 2) void fused_k(
    const unsigned short* __restrict__ A,   // [M][K] bf16
    const unsigned short* __restrict__ Bt,  // [1024][K] bf16 (W transposed)
    const float* __restrict__ bias, const float* __restrict__ g,
    const float* __restrict__ be, const float* __restrict__ Wh,
    const float* __restrict__ qoff,
    unsigned short* __restrict__ Hout, float* __restrict__ Qout,
    int K, int NT) {
  extern __shared__ unsigned short sm[];
  __shared__ float part[8][64][2];
  __shared__ float murs[64][2];
  __shared__ float dotf[64];
  __shared__ float qof[64];

  const int tid = threadIdx.x;
  const int w = tid >> 6, l = tid & 63;
  const int r0 = (int)blockIdx.x * 64;
  const int sb = (int)blockIdx.x % NT;          // K-order stagger

  // staging lane mapping (r5/r11-verified): row-block row (l>>3), slot l&7;
  // source col inverse-swizzled (st_16x32). (row&4) == ((l>>3)&4) for all
  // 8-row-aligned bases used here.
  const int sce = ((((l & 7) << 4) ^ (((l >> 3) & 4) << 3)) >> 1);
  // fragment-read constants (byte offsets)
  const int lr = (l & 15) << 7;
  const int cSw = (((l >> 4) << 4) ^ ((l & 4) << 3));

  f32x4 acc[4][8] = {};

#define KT(x) ((((x) + sb) % NT) << 6)
#define AF(d, mi, kk) (*(const bf16x8*)(sm + (((d)*8192 + (mi)*2048 + lr + cSw + ((kk) << 6)) >> 1)))
#define BFW(ni, kk) (*(const bf16x8*)(sm + ((16384 + w*16384 + (ni)*2048 + lr + cSw + ((kk) << 6)) >> 1)))
#define ISSUE_A(d, kt) \
    gload_lds16(A + (size_t)(r0 + w * 8 + (l >> 3)) * K + (kt) + sce, \
                sm + (((d)*8192 + w * 1024) >> 1))
#define ISSUE_B(kt) do { _Pragma("unroll") for (int i_ = 0; i_ < 16; ++i_) \
    gload_lds16(Bt + (size_t)(w * 128 + i_ * 8 + (l >> 3)) * K + (kt) + sce, \
                sm + ((16384 + w * 16384 + i_ * 1024) >> 1)); } while (0)
#define BAR() __builtin_amdgcn_s_barrier()
#define WAITLGKM() asm volatile("s_waitcnt lgkmcnt(0)" ::: "memory")
#define WAITVM(n) asm volatile("s_waitcnt vmcnt(" #n ")" ::: "memory")

  // prologue: A(0), B(0), A(1); drain A(0) (keep 17); publish
  ISSUE_A(0, KT(0));
  ISSUE_B(KT(0));
  ISSUE_A(1, KT(1));
  WAITVM(17); BAR();

  for (int t = 0; t < NT; ++t) {
    const int d = t & 1;
    // entry: drain B(t) (keep A(t+1) if it exists)
    if (t + 1 < NT) { WAITVM(1); } else { WAITVM(0); }
    bf16x8 af[4], bfr[8];
    // kk = 0
#pragma unroll
    for (int mi = 0; mi < 4; ++mi) af[mi] = AF(d, mi, 0);
#pragma unroll
    for (int ni = 0; ni < 8; ++ni) bfr[ni] = BFW(ni, 0);
    __builtin_amdgcn_s_setprio(1);
#pragma unroll
    for (int mi = 0; mi < 4; ++mi)
#pragma unroll
      for (int ni = 0; ni < 8; ++ni)
        acc[mi][ni] = __builtin_amdgcn_mfma_f32_16x16x32_bf16(af[mi], bfr[ni], acc[mi][ni], 0, 0, 0);
    __builtin_amdgcn_s_setprio(0);
    // kk = 1
#pragma unroll
    for (int mi = 0; mi < 4; ++mi) af[mi] = AF(d, mi, 1);
#pragma unroll
    for (int ni = 0; ni < 8; ++ni) bfr[ni] = BFW(ni, 1);
    WAITLGKM();                      // all tile-t LDS reads landed
    if (t + 1 < NT) ISSUE_B(KT(t + 1));   // wave-private overwrite, safe
    __builtin_amdgcn_s_setprio(1);
#pragma unroll
    for (int mi = 0; mi < 4; ++mi)
#pragma unroll
      for (int ni = 0; ni < 8; ++ni)
        acc[mi][ni] = __builtin_amdgcn_mfma_f32_16x16x32_bf16(af[mi], bfr[ni], acc[mi][ni], 0, 0, 0);
    __builtin_amdgcn_s_setprio(0);
    // drain own A(t+1) write before publishing barrier (keep B(t+1) x16)
    if (t + 1 < NT) { WAITVM(16); }
    BAR();
    if (t + 2 < NT) ISSUE_A(d, KT(t + 2));  // into just-read abuf, post-barrier
  }

  // ---------------- epilogue (r11-verified) ----------------
  float bcol[8], gcol[8], becol[8];
#pragma unroll
  for (int ni = 0; ni < 8; ++ni) {
    const int col = w * 128 + ni * 16 + (l & 15);
    bcol[ni] = bias[col];
    gcol[ni] = g[col];
    becol[ni] = be[col];
  }
#pragma unroll
  for (int mi = 0; mi < 4; ++mi)
#pragma unroll
    for (int rr = 0; rr < 4; ++rr) {
      float s1 = 0.f, s2 = 0.f;
#pragma unroll
      for (int ni = 0; ni < 8; ++ni) {
        const float x = acc[mi][ni][rr] + bcol[ni];
        s1 += x; s2 += x * x;
      }
#pragma unroll
      for (int o = 1; o < 16; o <<= 1) {
        s1 += __shfl_xor(s1, o, 64);
        s2 += __shfl_xor(s2, o, 64);
      }
      if ((l & 15) == 0) {
        const int row = mi * 16 + (l >> 4) * 4 + rr;
        part[w][row][0] = s1;
        part[w][row][1] = s2;
      }
    }
  __syncthreads();
  if (tid < 64) {
    float s1 = 0.f, s2 = 0.f;
#pragma unroll
    for (int ww = 0; ww < 8; ++ww) { s1 += part[ww][tid][0]; s2 += part[ww][tid][1]; }
    const float mu = s1 * (1.0f / HID);
    murs[tid][0] = mu;
    murs[tid][1] = rsqrtf(s2 * (1.0f / HID) - mu * mu + 1e-5f);
    if (FINAL) qof[tid] = qoff[tid];
  }
  __syncthreads();

  if (!FINAL) {
#pragma unroll
    for (int mi = 0; mi < 4; ++mi)
#pragma unroll
      for (int rr = 0; rr < 4; ++rr) {
        const int row = mi * 16 + (l >> 4) * 4 + rr;
        const float mu = murs[row][0], rs = murs[row][1];
        unsigned short* hp = Hout + (size_t)(r0 + row) * HID + w * 128 + (l & 15);
#pragma unroll
        for (int ni = 0; ni < 8; ++ni) {
          const float x = acc[mi][ni][rr] + bcol[ni];
          hp[ni * 16] = f2bf(fmaxf((x - mu) * rs * gcol[ni] + becol[ni], 0.f));
        }
      }
  } else {
    float wf[8];
#pragma unroll
    for (int ni = 0; ni < 8; ++ni) wf[ni] = Wh[w * 128 + ni * 16 + (l & 15)];
#pragma unroll
    for (int mi = 0; mi < 4; ++mi)
#pragma unroll
      for (int rr = 0; rr < 4; ++rr) {
        const int row = mi * 16 + (l >> 4) * 4 + rr;
        const float mu = murs[row][0], rs = murs[row][1];
        float dp = 0.f;
#pragma unroll
        for (int ni = 0; ni < 8; ++ni) {
          const float x = acc[mi][ni][rr] + bcol[ni];
          dp += fmaxf((x - mu) * rs * gcol[ni] + becol[ni], 0.f) * wf[ni];
        }
#pragma unroll
        for (int o = 1; o < 16; o <<= 1) dp += __shfl_xor(dp, o, 64);
        if ((l & 15) == 0) part[w][row][0] = dp;
      }
    __syncthreads();
    if (tid < 64) {
      float dsum = 0.f;
#pragma unroll
      for (int ww = 0; ww < 8; ++ww) dsum += part[ww][tid][0];
      dotf[tid] = dsum;
    }
    __syncthreads();
#pragma unroll
    for (int it = 0; it < 8; ++it) {
      const int idx = tid + it * 512;
      const int row = idx >> 6, q = idx & 63;
      Qout[(size_t)(r0 + row) * NQ + q] = dotf[row] + qof[q];
    }
  }
#undef KT
#undef AF
#undef BFW
#undef ISSUE_A
#undef ISSUE_B
#undef BAR
#undef WAITLGKM
#undef WAITVM
}

extern "C" void kernel_launch(void* const* d_in, const int* in_sizes, int n_in,
                              void* d_out, int out_size, void* d_ws, size_t ws_size,
                              hipStream_t stream) {
  const float* state  = (const float*)d_in[0];
  const float* action = (const float*)d_in[1];
  const float* W1  = (const float*)d_in[2];
  const float* b1  = (const float*)d_in[3];
  const float* g1  = (const float*)d_in[4];
  const float* be1 = (const float*)d_in[5];
  const float* W2  = (const float*)d_in[6];
  const float* b2  = (const float*)d_in[7];
  const float* g2  = (const float*)d_in[8];
  const float* be2 = (const float*)d_in[9];
  const float* Wq1 = (const float*)d_in[10];
  const float* bq1 = (const float*)d_in[11];
  const float* Wq2 = (const float*)d_in[12];
  const float* bq2 = (const float*)d_in[13];
  const float* Wh  = (const float*)d_in[14];
  const float* bh  = (const float*)d_in[15];
  float* out = (float*)d_out;

  // workspace (~56 MB)
  char* ws = (char*)d_ws;
  size_t off = 0;
  float* qoff = (float*)(ws + off); off += 256;
  unsigned short* xb  = (unsigned short*)(ws + off); off += (size_t)B_ROWS * KDIM * 2; // 18.87 MB
  unsigned short* w1b = (unsigned short*)(ws + off); off += (size_t)HID * KDIM * 2;    // 1.18 MB
  unsigned short* w2b = (unsigned short*)(ws + off); off += (size_t)HID * HID * 2;     // 2.10 MB
  unsigned short* h1b = (unsigned short*)(ws + off);                                   // 33.55 MB

  (void)hipFuncSetAttribute((const void*)fused_k<false>, hipFuncAttributeMaxDynamicSharedMemorySize, FK_LDS);
  (void)hipFuncSetAttribute((const void*)fused_k<true>, hipFuncAttributeMaxDynamicSharedMemorySize, FK_LDS);

  prep_k<<<PREP_BLOCKS, 256, 0, stream>>>(state, action, W1, W2, Wq1, bq1, Wq2, bq2,
                                          Wh, bh, xb, w1b, w2b, qoff);

  // layer 1: h1 = relu(LN(x@W1 + b1))  -> h1b (bf16)
  fused_k<false><<<B_ROWS / 64, 512, FK_LDS, stream>>>(
      xb, w1b, b1, g1, be1, nullptr, nullptr, h1b, nullptr, KDIM, KDIM / 64);
  // layer 2 + head: out = relu(LN(h1@W2 + b2)) @ Wf + qoff
  fused_k<true><<<B_ROWS / 64, 512, FK_LDS, stream>>>(
      h1b, w2b, b2, g2, be2, Wh, qoff, nullptr, out, HID, HID / 64);
}

// Round 13
// 107.783 us; speedup vs baseline: 1.4800x; 1.0056x over previous
//
#include <hip/hip_runtime.h>
#include <hip/hip_bf16.h>
#include <cstddef>

// Problem constants
#define B_ROWS 16384
#define SDIM 512
#define ADIM 64
#define KDIM 576    // SDIM + ADIM = 9 K-tiles of 64 (exact)
#define HID 1024
#define NQ 64

// prep: transposes + qoff only (x is consumed raw by fused1)
#define T1_BLOCKS ((KDIM / 32) * (HID / 32))   // 576
#define T2_BLOCKS ((HID / 32) * (HID / 32))    // 1024
#define PREP_BLOCKS (T1_BLOCKS + T2_BLOCKS + 1)

#define FK_LDS (16384 + 131072)   // A double-buffer (2x8KB) + B (8 waves x 16KB)

typedef __attribute__((ext_vector_type(8))) __bf16 bf16x8;
typedef __attribute__((ext_vector_type(4))) float f32x4;

static __device__ __forceinline__ float bf2f(unsigned short u) {
  union { unsigned int i; float f; } x; x.i = ((unsigned int)u) << 16; return x.f;
}
static __device__ __forceinline__ unsigned short f2bf(float f) {
  union { float f; unsigned int i; } x; x.f = f;
  unsigned int i = x.i + (0x7fffu + ((x.i >> 16) & 1u)); // RNE
  return (unsigned short)(i >> 16);
}

static __device__ __forceinline__ void gload_lds16(const unsigned short* g, unsigned short* l) {
  __builtin_amdgcn_global_load_lds(
      (const __attribute__((address_space(1))) void*)(const void*)g,
      (__attribute__((address_space(3))) void*)(void*)l, 16, 0, 0);
}

// pack 8 f32 -> 8 bf16 (RNE) in one uint4
static __device__ __forceinline__ uint4 pack8(float4 a, float4 b) {
  uint4 o;
  o.x = (unsigned)f2bf(a.x) | ((unsigned)f2bf(a.y) << 16);
  o.y = (unsigned)f2bf(a.z) | ((unsigned)f2bf(a.w) << 16);
  o.z = (unsigned)f2bf(b.x) | ((unsigned)f2bf(b.y) << 16);
  o.w = (unsigned)f2bf(b.z) | ((unsigned)f2bf(b.w) << 16);
  return o;
}

// ---- transpose helper: W [Kin][N] f32 -> Wb [N][Kin] bf16 ----
static __device__ __forceinline__ void transpose_body(
    const float* __restrict__ W, unsigned short* __restrict__ Wb,
    int Kin, int N, int k0, int n0, unsigned short* tile) {
  const int tx = threadIdx.x & 31, ty = threadIdx.x >> 5;
#pragma unroll
  for (int i = 0; i < 32; i += 8)
    tile[(ty + i) * 33 + tx] = f2bf(W[(size_t)(k0 + ty + i) * N + n0 + tx]);
  __syncthreads();
#pragma unroll
  for (int i = 0; i < 32; i += 8)
    Wb[(size_t)(n0 + ty + i) * Kin + k0 + tx] = tile[tx * 33 + ty + i];
}

// ---- prep: weight transposes + qoff (tiny) ----
__global__ __launch_bounds__(256) void prep_k(
    const float* __restrict__ W1, const float* __restrict__ W2,
    const float* __restrict__ Wq1, const float* __restrict__ bq1,
    const float* __restrict__ Wq2, const float* __restrict__ bq2,
    const float* __restrict__ Wh, const float* __restrict__ bh,
    unsigned short* __restrict__ w1b, unsigned short* __restrict__ w2b,
    float* __restrict__ qoff) {
  __shared__ unsigned short tile[32 * 33];
  const int b = blockIdx.x;
  if (b < T1_BLOCKS) {
    transpose_body(W1, w1b, KDIM, HID, (b / 32) * 32, (b % 32) * 32, tile);
  } else if (b < T1_BLOCKS + T2_BLOCKS) {
    const int t = b - T1_BLOCKS;
    transpose_body(W2, w2b, HID, HID, (t / 32) * 32, (t % 32) * 32, tile);
  } else {
    const int q = threadIdx.x;
    if (q < NQ) {
      const float tau = ((float)q + 0.5f) * (1.0f / (float)NQ);
      float t1[64];
#pragma unroll
      for (int k = 0; k < 64; ++k) t1[k] = fmaxf(fmaf(tau, Wq1[k], bq1[k]), 0.f);
      float acc = bh[0];
#pragma unroll 1
      for (int j = 0; j < 64; ++j) {
        float t2 = bq2[j];
#pragma unroll
        for (int k = 0; k < 64; ++k) t2 = fmaf(t1[k], Wq2[k * 64 + j], t2);
        acc = fmaf(t2, Wh[HID + j], acc);
      }
      qoff[q] = acc;
    }
  }
}

// ============================================================================
// Pipelined row-stripe fused GEMM+LN (r12-verified skeleton).
// Block = 64 rows x ALL 1024 out-cols; 512 thr = 8 waves; wave w owns cols
// w*128..+127 => B-chunk w is wave-private (no barriers for B, counted vmcnt).
// A double-buffered (2x8KB), 1 barrier/tile.
//  XSRC=true : A = concat(state,action) f32, converted in-register during
//              staging (tiles 0-7 = state, tile kt=512 = action). Ledger:
//              entry vmcnt(2) [drain B(t), keep A(t+1) regs]; AWRX mid-tile
//              (auto-waits A-regs, oldest -> B(t+1) stays); lgkm(0)+BAR
//              commits ds_write; post-BAR ALOADX(t+2).
//  XSRC=false: A = bf16 via global_load_lds (r12 path: vmcnt 17/1/16).
// Epilogue (r11/r12-verified): cross-wave LDS tree-reduce row mean/var,
// LN+ReLU on f32 accs; FINAL adds rank-1 Wf-dot + qoff -> f32 out.
// ============================================================================
template <bool XSRC, bool FINAL>
__global__ __launch_bounds__(512, 2) void fused_k(
    const float* __restrict__ Xs,           // state  [M][512]   (XSRC)
    const float* __restrict__ Xa,           // action [M][64]    (XSRC)
    const unsigned short* __restrict__ A,   // [M][K] bf16       (!XSRC)
    const unsigned short* __restrict__ Bt,  // [1024][K] bf16 (W transposed)
    const float* __restrict__ bias, const float* __restrict__ g,
    const float* __restrict__ be, const float* __restrict__ Wh,
    const float* __restrict__ qoff,
    unsigned short* __restrict__ Hout, float* __restrict__ Qout,
    int K, int NT) {
  extern __shared__ unsigned short sm[];
  __shared__ float part[8][64][2];
  __shared__ float murs[64][2];
  __shared__ float dotf[64];
  __shared__ float qof[64];

  const int tid = threadIdx.x;
  const int w = tid >> 6, l = tid & 63;
  const int r0 = (int)blockIdx.x * 64;
  const int sb = (int)blockIdx.x % NT;          // K-order stagger

  const int sce = ((((l & 7) << 4) ^ (((l >> 3) & 4) << 3)) >> 1);
  const int lr = (l & 15) << 7;
  const int cSw = (((l >> 4) << 4) ^ ((l & 4) << 3));

  f32x4 acc[4][8] = {};
  float4 ar0, ar1;   // XSRC: next A-tile f32 in flight (8 floats/lane)

#define KT(x) ((((x) + sb) % NT) << 6)
#define AF(d, mi, kk) (*(const bf16x8*)(sm + (((d)*8192 + (mi)*2048 + lr + cSw + ((kk) << 6)) >> 1)))
#define BFW(ni, kk) (*(const bf16x8*)(sm + ((16384 + w*16384 + (ni)*2048 + lr + cSw + ((kk) << 6)) >> 1)))
#define ISSUE_A(d, kt) \
    gload_lds16(A + (size_t)(r0 + w * 8 + (l >> 3)) * K + (kt) + sce, \
                sm + (((d)*8192 + w * 1024) >> 1))
#define ALOADX(kt) do { \
    const int row_ = r0 + w * 8 + (l >> 3); \
    if ((kt) < SDIM) { const float* p_ = Xs + (size_t)row_ * SDIM + (kt) + sce; \
      ar0 = *(const float4*)p_; ar1 = *(const float4*)(p_ + 4); } \
    else { const float* p_ = Xa + (size_t)row_ * ADIM + ((kt) - SDIM) + sce; \
      ar0 = *(const float4*)p_; ar1 = *(const float4*)(p_ + 4); } } while (0)
#define AWRX(d) (*(uint4*)(sm + (((d)*8192 + w * 1024 + l * 16) >> 1)) = pack8(ar0, ar1))
#define ISSUE_B(kt) do { _Pragma("unroll") for (int i_ = 0; i_ < 16; ++i_) \
    gload_lds16(Bt + (size_t)(w * 128 + i_ * 8 + (l >> 3)) * K + (kt) + sce, \
                sm + ((16384 + w * 16384 + i_ * 1024) >> 1)); } while (0)
#define BAR() __builtin_amdgcn_s_barrier()
#define WAITLGKM() asm volatile("s_waitcnt lgkmcnt(0)" ::: "memory")
#define WAITVM(n) asm volatile("s_waitcnt vmcnt(" #n ")" ::: "memory")

  // prologue
  if (XSRC) {
    ALOADX(KT(0)); AWRX(0);          // serial load->cvt->write for tile 0
    ISSUE_B(KT(0));
    if (NT > 1) ALOADX(KT(1));       // A(1) f32 regs in flight
    WAITLGKM(); BAR();               // commit abuf0; B(0)+A(1) outstanding
  } else {
    ISSUE_A(0, KT(0));
    ISSUE_B(KT(0));
    ISSUE_A(1, KT(1));
    WAITVM(17); BAR();               // drain A(0) write only
  }

  for (int t = 0; t < NT; ++t) {
    const int d = t & 1;
    // entry: drain B(t), keep next-A in flight
    if (t + 1 < NT) { if (XSRC) { WAITVM(2); } else { WAITVM(1); } }
    else { WAITVM(0); }
    bf16x8 af[4], bfr[8];
    // kk = 0
#pragma unroll
    for (int mi = 0; mi < 4; ++mi) af[mi] = AF(d, mi, 0);
#pragma unroll
    for (int ni = 0; ni < 8; ++ni) bfr[ni] = BFW(ni, 0);
    __builtin_amdgcn_s_setprio(1);
#pragma unroll
    for (int mi = 0; mi < 4; ++mi)
#pragma unroll
      for (int ni = 0; ni < 8; ++ni)
        acc[mi][ni] = __builtin_amdgcn_mfma_f32_16x16x32_bf16(af[mi], bfr[ni], acc[mi][ni], 0, 0, 0);
    __builtin_amdgcn_s_setprio(0);
    // kk = 1
#pragma unroll
    for (int mi = 0; mi < 4; ++mi) af[mi] = AF(d, mi, 1);
#pragma unroll
    for (int ni = 0; ni < 8; ++ni) bfr[ni] = BFW(ni, 1);
    WAITLGKM();                           // tile-t LDS reads landed
    if (t + 1 < NT) ISSUE_B(KT(t + 1));   // wave-private overwrite, safe
    if (XSRC && t + 1 < NT) AWRX((t + 1) & 1);  // cvt+write A(t+1); auto-waits A-regs
    __builtin_amdgcn_s_setprio(1);
#pragma unroll
    for (int mi = 0; mi < 4; ++mi)
#pragma unroll
      for (int ni = 0; ni < 8; ++ni)
        acc[mi][ni] = __builtin_amdgcn_mfma_f32_16x16x32_bf16(af[mi], bfr[ni], acc[mi][ni], 0, 0, 0);
    __builtin_amdgcn_s_setprio(0);
    if (XSRC) {
      if (t + 1 < NT) { WAITLGKM(); }     // commit AWRX ds_write pre-barrier
      BAR();
      if (t + 2 < NT) ALOADX(KT(t + 2));  // next A f32 regs, post-barrier
    } else {
      if (t + 1 < NT) { WAITVM(16); }     // drain own A(t+1) glds write
      BAR();
      if (t + 2 < NT) ISSUE_A(d, KT(t + 2));
    }
  }

  // ---------------- epilogue (r12-verified) ----------------
  float bcol[8], gcol[8], becol[8];
#pragma unroll
  for (int ni = 0; ni < 8; ++ni) {
    const int col = w * 128 + ni * 16 + (l & 15);
    bcol[ni] = bias[col];
    gcol[ni] = g[col];
    becol[ni] = be[col];
  }
#pragma unroll
  for (int mi = 0; mi < 4; ++mi)
#pragma unroll
    for (int rr = 0; rr < 4; ++rr) {
      float s1 = 0.f, s2 = 0.f;
#pragma unroll
      for (int ni = 0; ni < 8; ++ni) {
        const float x = acc[mi][ni][rr] + bcol[ni];
        s1 += x; s2 += x * x;
      }
#pragma unroll
      for (int o = 1; o < 16; o <<= 1) {
        s1 += __shfl_xor(s1, o, 64);
        s2 += __shfl_xor(s2, o, 64);
      }
      if ((l & 15) == 0) {
        const int row = mi * 16 + (l >> 4) * 4 + rr;
        part[w][row][0] = s1;
        part[w][row][1] = s2;
      }
    }
  __syncthreads();
  if (tid < 64) {
    float s1 = 0.f, s2 = 0.f;
#pragma unroll
    for (int ww = 0; ww < 8; ++ww) { s1 += part[ww][tid][0]; s2 += part[ww][tid][1]; }
    const float mu = s1 * (1.0f / HID);
    murs[tid][0] = mu;
    murs[tid][1] = rsqrtf(s2 * (1.0f / HID) - mu * mu + 1e-5f);
    if (FINAL) qof[tid] = qoff[tid];
  }
  __syncthreads();

  if (!FINAL) {
#pragma unroll
    for (int mi = 0; mi < 4; ++mi)
#pragma unroll
      for (int rr = 0; rr < 4; ++rr) {
        const int row = mi * 16 + (l >> 4) * 4 + rr;
        const float mu = murs[row][0], rs = murs[row][1];
        unsigned short* hp = Hout + (size_t)(r0 + row) * HID + w * 128 + (l & 15);
#pragma unroll
        for (int ni = 0; ni < 8; ++ni) {
          const float x = acc[mi][ni][rr] + bcol[ni];
          hp[ni * 16] = f2bf(fmaxf((x - mu) * rs * gcol[ni] + becol[ni], 0.f));
        }
      }
  } else {
    float wf[8];
#pragma unroll
    for (int ni = 0; ni < 8; ++ni) wf[ni] = Wh[w * 128 + ni * 16 + (l & 15)];
#pragma unroll
    for (int mi = 0; mi < 4; ++mi)
#pragma unroll
      for (int rr = 0; rr < 4; ++rr) {
        const int row = mi * 16 + (l >> 4) * 4 + rr;
        const float mu = murs[row][0], rs = murs[row][1];
        float dp = 0.f;
#pragma unroll
        for (int ni = 0; ni < 8; ++ni) {
          const float x = acc[mi][ni][rr] + bcol[ni];
          dp += fmaxf((x - mu) * rs * gcol[ni] + becol[ni], 0.f) * wf[ni];
        }
#pragma unroll
        for (int o = 1; o < 16; o <<= 1) dp += __shfl_xor(dp, o, 64);
        if ((l & 15) == 0) part[w][row][0] = dp;
      }
    __syncthreads();
    if (tid < 64) {
      float dsum = 0.f;
#pragma unroll
      for (int ww = 0; ww < 8; ++ww) dsum += part[ww][tid][0];
      dotf[tid] = dsum;
    }
    __syncthreads();
#pragma unroll
    for (int it = 0; it < 8; ++it) {
      const int idx = tid + it * 512;
      const int row = idx >> 6, q = idx & 63;
      Qout[(size_t)(r0 + row) * NQ + q] = dotf[row] + qof[q];
    }
  }
#undef KT
#undef AF
#undef BFW
#undef ISSUE_A
#undef ALOADX
#undef AWRX
#undef ISSUE_B
#undef BAR
#undef WAITLGKM
#undef WAITVM
}

extern "C" void kernel_launch(void* const* d_in, const int* in_sizes, int n_in,
                              void* d_out, int out_size, void* d_ws, size_t ws_size,
                              hipStream_t stream) {
  const float* state  = (const float*)d_in[0];
  const float* action = (const float*)d_in[1];
  const float* W1  = (const float*)d_in[2];
  const float* b1  = (const float*)d_in[3];
  const float* g1  = (const float*)d_in[4];
  const float* be1 = (const float*)d_in[5];
  const float* W2  = (const float*)d_in[6];
  const float* b2  = (const float*)d_in[7];
  const float* g2  = (const float*)d_in[8];
  const float* be2 = (const float*)d_in[9];
  const float* Wq1 = (const float*)d_in[10];
  const float* bq1 = (const float*)d_in[11];
  const float* Wq2 = (const float*)d_in[12];
  const float* bq2 = (const float*)d_in[13];
  const float* Wh  = (const float*)d_in[14];
  const float* bh  = (const float*)d_in[15];
  float* out = (float*)d_out;

  // workspace (~37 MB)
  char* ws = (char*)d_ws;
  size_t off = 0;
  float* qoff = (float*)(ws + off); off += 256;
  unsigned short* w1b = (unsigned short*)(ws + off); off += (size_t)HID * KDIM * 2;    // 1.18 MB
  unsigned short* w2b = (unsigned short*)(ws + off); off += (size_t)HID * HID * 2;     // 2.10 MB
  unsigned short* h1b = (unsigned short*)(ws + off);                                   // 33.55 MB

  (void)hipFuncSetAttribute((const void*)fused_k<true, false>, hipFuncAttributeMaxDynamicSharedMemorySize, FK_LDS);
  (void)hipFuncSetAttribute((const void*)fused_k<false, true>, hipFuncAttributeMaxDynamicSharedMemorySize, FK_LDS);

  prep_k<<<PREP_BLOCKS, 256, 0, stream>>>(W1, W2, Wq1, bq1, Wq2, bq2, Wh, bh,
                                          w1b, w2b, qoff);

  // layer 1: h1 = relu(LN(concat(state,action)@W1 + b1)) -> h1b (bf16)
  fused_k<true, false><<<B_ROWS / 64, 512, FK_LDS, stream>>>(
      state, action, nullptr, w1b, b1, g1, be1, nullptr, nullptr,
      h1b, nullptr, KDIM, KDIM / 64);
  // layer 2 + head: out = relu(LN(h1@W2 + b2)) @ Wf + qoff
  fused_k<false, true><<<B_ROWS / 64, 512, FK_LDS, stream>>>(
      nullptr, nullptr, h1b, w2b, b2, g2, be2, Wh, qoff,
      nullptr, out, HID, HID / 64);
}